// Round 1
// baseline (1004.123 us; speedup 1.0000x reference)
//
#include <hip/hip_runtime.h>
#include <hip/hip_bf16.h>

#define NN 6000
#define NPAD 6016      // 94*64
#define DF 512
#define HID 256
#define NH 8
#define NC 32
#define FTOT 2048
#define MSTR 96        // u64 words per mask row (stride)

using short8 = __attribute__((ext_vector_type(8))) short;
using f32x16 = __attribute__((ext_vector_type(16))) float;
using f32x4  = __attribute__((ext_vector_type(4))) float;

__device__ __forceinline__ unsigned short f2bf(float f) {
    unsigned int u = __float_as_uint(f);
    return (unsigned short)((u + 0x7fffu + ((u >> 16) & 1u)) >> 16);
}
__device__ __forceinline__ float bf2f(unsigned short s) {
    return __uint_as_float(((unsigned int)s) << 16);
}

// ---------------- prep kernels ----------------

// adj [6000][6000] int32 -> bitmask [6000][MSTR] u64 (pad bits zero)
__global__ void pack_bits(const int* __restrict__ adj, unsigned long long* __restrict__ mask) {
    int row = blockIdx.x;
    int wv = threadIdx.x >> 6, lane = threadIdx.x & 63;
    for (int word = wv; word < MSTR; word += 4) {
        int j = word * 64 + lane;
        int a = (j < NN) ? adj[(long long)row * NN + j] : 0;
        unsigned long long b = __ballot(a > 0);
        if (lane == 0) mask[(size_t)row * MSTR + word] = b;
    }
}

__global__ void cast_x(const float* __restrict__ x, unsigned short* __restrict__ xb, int n) {
    int i = blockIdx.x * blockDim.x + threadIdx.x;
    if (i < n) xb[i] = f2bf(x[i]);
}

// W0 [8][512][256] -> Wt [2048][512], Wt[h*256+f][k] = W0[h][k][f]
__global__ void wt_pack(const float* __restrict__ W0, unsigned short* __restrict__ Wt) {
    int id = blockIdx.x * blockDim.x + threadIdx.x;
    if (id >= NH * DF * HID) return;
    int f = id & 255, k = (id >> 8) & 511, h = id >> 17;
    Wt[(size_t)((h << 8) + f) * DF + k] = f2bf(W0[id]);
}

// Wc [2048][32] -> Wct [32][2048]
__global__ void wct_pack(const float* __restrict__ Wc, unsigned short* __restrict__ Wct) {
    int id = blockIdx.x * blockDim.x + threadIdx.x;
    if (id >= FTOT * NC) return;
    int c = id & 31, k = id >> 5;
    Wct[(size_t)c * FTOT + k] = f2bf(Wc[id]);
}

// ---------------- GEMM1: Ht[f][i] = sum_k X[i][k] W[k][f]  (bf16 MFMA) ----------------
__global__ __launch_bounds__(256, 2) void gemm_h(const unsigned short* __restrict__ A,   // Xbf [6000][512]
                                                 const unsigned short* __restrict__ B,   // Wt  [2048][512]
                                                 unsigned short* __restrict__ Ht) {      // [2048][NPAD]
    int w = threadIdx.x >> 6, l = threadIdx.x & 63;
    int lrow = l & 31, kh = l >> 5;
    int mbase = blockIdx.x * 128 + w * 32;
    int nbase = blockIdx.y * 128;
    int arow = mbase + lrow; if (arow > NN - 1) arow = NN - 1;   // clamp: keeps pad rows finite
    const short8* ap = (const short8*)(A + (size_t)arow * DF + kh * 8);
    f32x16 acc[4];
#pragma unroll
    for (int i = 0; i < 4; ++i) acc[i] = (f32x16)0.0f;
    for (int kk = 0; kk < DF / 16; ++kk) {
        short8 af = ap[kk * 2];
#pragma unroll
        for (int ft = 0; ft < 4; ++ft) {
            short8 bf = *(const short8*)(B + (size_t)(nbase + ft * 32 + lrow) * DF + kk * 16 + kh * 8);
            acc[ft] = __builtin_amdgcn_mfma_f32_32x32x16_bf16(af, bf, acc[ft], 0, 0, 0);
        }
    }
    // C/D: col = lane&31 (n), row = (reg&3)+8*(reg>>2)+4*kh (m)
#pragma unroll
    for (int ft = 0; ft < 4; ++ft) {
        size_t n = nbase + ft * 32 + lrow;
#pragma unroll
        for (int g = 0; g < 4; ++g) {
            int m0 = mbase + (g << 3) + (kh << 2);
            unsigned long long pk =
                (unsigned long long)f2bf(acc[ft][g * 4 + 0]) |
                ((unsigned long long)f2bf(acc[ft][g * 4 + 1]) << 16) |
                ((unsigned long long)f2bf(acc[ft][g * 4 + 2]) << 32) |
                ((unsigned long long)f2bf(acc[ft][g * 4 + 3]) << 48);
            *(unsigned long long*)(Ht + n * NPAD + m0) = pk;
        }
    }
}

// f1[h][i] = sum_f Ht[h*fdim+f][i]*a1[h*fdim+f]; f2 likewise
__global__ void f12_kern(const unsigned short* __restrict__ Ht, const float* __restrict__ a1,
                         const float* __restrict__ a2, float* __restrict__ f1, float* __restrict__ f2,
                         int fdim) {
    int h = blockIdx.y;
    int i = blockIdx.x * 256 + threadIdx.x;
    if (i >= NPAD) return;
    float s1 = 0.f, s2 = 0.f;
    const unsigned short* base = Ht + (size_t)h * fdim * NPAD + i;
    for (int f = 0; f < fdim; ++f) {
        float v = bf2f(base[(size_t)f * NPAD]);
        s1 = fmaf(v, a1[h * fdim + f], s1);
        s2 = fmaf(v, a2[h * fdim + f], s2);
    }
    f1[h * NPAD + i] = s1;
    f2[h * NPAD + i] = s2;
}

// per (h,i): m = max_{j in N(i)} f2[j]; M = lrelu(f1+m); RA = f1-M; RB = 0.2*f1-M
__global__ void prep_rows(const unsigned long long* __restrict__ mask,
                          const float* __restrict__ f1, const float* __restrict__ f2,
                          float* __restrict__ RA, float* __restrict__ RB, int nh) {
    int gw = (blockIdx.x * blockDim.x + threadIdx.x) >> 6;
    int lane = threadIdx.x & 63;
    if (gw >= nh * NPAD) return;
    int h = gw / NPAD, i = gw - h * NPAD;
    float m = -3.0e38f;
    if (i < NN) {
        const unsigned long long* mrow = mask + (size_t)i * MSTR;
        const float* f2h = f2 + h * NPAD;
        for (int t = 0; t < 94; ++t) {
            unsigned long long wbits = mrow[t];
            if ((wbits >> lane) & 1ull) m = fmaxf(m, f2h[t * 64 + lane]);
        }
    }
    for (int off = 32; off; off >>= 1) m = fmaxf(m, __shfl_xor(m, off));
    if (lane == 0) {
        float F1 = 0.f, M = 0.f;
        if (i < NN) {
            F1 = f1[h * NPAD + i];
            float t = F1 + m;
            M = fmaxf(t, 0.2f * t);
        }
        RA[h * NPAD + i] = F1 - M;
        RB[h * NPAD + i] = 0.2f * F1 - M;
    }
}

__global__ void prep_f2s(const float* __restrict__ f2, float* __restrict__ F2,
                         float* __restrict__ F2b, int n) {
    int i = blockIdx.x * blockDim.x + threadIdx.x;
    if (i < n) { float v = f2[i]; F2[i] = v; F2b[i] = 0.2f * v; }
}

// ---------------- flash-style masked softmax-aggregation ----------------
// out_i = (1/d_i) * sum_j bit(i,j)*exp(max(RA_i+f2_j, RB_i+0.2 f2_j)) * H[j][:]
template<int F, bool STORE_X2>
__global__ __launch_bounds__(256, 2) void attn_kern(
    const unsigned short* __restrict__ Hall,          // [nh*F][NPAD] (transposed h)
    const unsigned long long* __restrict__ mask,
    const float* __restrict__ RA, const float* __restrict__ RB,
    const float* __restrict__ F2, const float* __restrict__ F2b,
    unsigned short* __restrict__ x2, float* __restrict__ outp)
{
    constexpr int NT = F / 32;
    __shared__ __align__(16) unsigned short htile[F * 64];   // [F][64] swizzled
    __shared__ unsigned int mtile[128 * 2];

    const int w = threadIdx.x >> 6, l = threadIdx.x & 63;
    const int lrow = l & 31, kh = l >> 5;
    const int h = blockIdx.y;
    const int rowbase = blockIdx.x * 128;
    const int myrow = rowbase + w * 32 + lrow;

    const unsigned short* Hh = Hall + (size_t)h * F * NPAD;
    const float* RAh = RA + h * NPAD;
    const float* RBh = RB + h * NPAD;
    const float* F2h = F2 + h * NPAD;
    const float* F2bh = F2b + h * NPAD;

    const float ra = RAh[myrow], rb = RBh[myrow];
    float dsum = 0.f;
    f32x16 acc[NT];
#pragma unroll
    for (int i = 0; i < NT; ++i) acc[i] = (f32x16)0.0f;

    for (int jb = 0; jb < NPAD / 64; ++jb) {
        __syncthreads();
        constexpr int CPT = (F * 8) / 256;
#pragma unroll
        for (int cc = 0; cc < CPT; ++cc) {
            int idx = threadIdx.x + cc * 256;
            int f = idx >> 3, c = idx & 7;
            uint4 g = *(const uint4*)(Hh + (size_t)f * NPAD + jb * 64 + c * 8);
            int byt = f * 128 + ((c * 16) ^ ((f & 7) << 4));
            *(uint4*)((char*)htile + byt) = g;
        }
        {
            int r = threadIdx.x >> 1, half = threadIdx.x & 1;
            int grow = rowbase + r;
            unsigned int mv = 0;
            if (grow < NN) mv = ((const unsigned int*)(mask + (size_t)grow * MSTR))[jb * 2 + half];
            mtile[r * 2 + half] = mv;
        }
        __syncthreads();
#pragma unroll
        for (int kk = 0; kk < 4; ++kk) {
            unsigned int mword = mtile[(w * 32 + lrow) * 2 + (kk >> 1)];
            unsigned int mbyte = (mword >> (((kk & 1) * 2 + kh) * 8)) & 0xffu;
            int j0 = jb * 64 + kk * 16 + kh * 8;
            f32x4 fa0 = *(const f32x4*)(F2h + j0);
            f32x4 fa1 = *(const f32x4*)(F2h + j0 + 4);
            f32x4 fb0 = *(const f32x4*)(F2bh + j0);
            f32x4 fb1 = *(const f32x4*)(F2bh + j0 + 4);
            short8 afrag;
#pragma unroll
            for (int e = 0; e < 8; ++e) {
                float fe = (e < 4) ? fa0[e & 3] : fa1[e & 3];
                float fb = (e < 4) ? fb0[e & 3] : fb1[e & 3];
                float p = __expf(fmaxf(ra + fe, rb + fb));
                p = ((mbyte >> e) & 1u) ? p : 0.f;
                dsum += p;
                afrag[e] = (short)f2bf(p);
            }
#pragma unroll
            for (int ft = 0; ft < NT; ++ft) {
                int fr = ft * 32 + lrow;
                int byt = fr * 128 + (((kk * 2 + kh) * 16) ^ ((fr & 7) << 4));
                short8 bfrag = *(const short8*)((char*)htile + byt);
                acc[ft] = __builtin_amdgcn_mfma_f32_32x32x16_bf16(afrag, bfrag, acc[ft], 0, 0, 0);
            }
        }
    }
    dsum += __shfl_xor(dsum, 32);
    float dinv = (dsum > 0.f) ? (1.0f / dsum) : 0.f;
    float rcp16[16];
#pragma unroll
    for (int g = 0; g < 4; ++g)
#pragma unroll
        for (int r = 0; r < 4; ++r)
            rcp16[g * 4 + r] = __shfl(dinv, (g << 3) + (kh << 2) + r);

    if constexpr (!STORE_X2) {
        // classifier: write fp32 out[i][c], c = lrow
#pragma unroll
        for (int g = 0; g < 4; ++g)
#pragma unroll
            for (int r = 0; r < 4; ++r) {
                int grow = rowbase + w * 32 + (g << 3) + (kh << 2) + r;
                if (grow < NN) outp[(size_t)grow * NC + lrow] = acc[0][g * 4 + r] * rcp16[g * 4 + r];
            }
    } else {
        // ELU + bf16 store of x2[i][h*256+f] via LDS transpose (2 waves per phase)
        unsigned short* tb = htile;
        for (int ph = 0; ph < 2; ++ph) {
            __syncthreads();
            if ((w >> 1) == ph) {
                unsigned short* wb = tb + (w & 1) * (32 * 256);
#pragma unroll
                for (int ft = 0; ft < NT; ++ft)
#pragma unroll
                    for (int g = 0; g < 4; ++g)
#pragma unroll
                        for (int r = 0; r < 4; ++r) {
                            int lr2 = (g << 3) + (kh << 2) + r;
                            float v = acc[ft][g * 4 + r] * rcp16[g * 4 + r];
                            v = (v > 0.f) ? v : (__expf(v) - 1.f);
                            wb[lr2 * 256 + ft * 32 + lrow] = f2bf(v);
                        }
            }
            __syncthreads();
            if ((w >> 1) == ph) {
                unsigned short* wb = tb + (w & 1) * (32 * 256);
                int r = l >> 1;
                int grow = rowbase + w * 32 + r;
                if (grow < NN) {
#pragma unroll
                    for (int it = 0; it < 16; ++it) {
                        int c = (l & 1) * 16 + it;
                        uint4 v = *(const uint4*)(wb + r * 256 + c * 8);
                        *(uint4*)(x2 + (size_t)grow * FTOT + h * HID + c * 8) = v;
                    }
                }
            }
        }
    }
}

// ---------------- GEMM2: hct[c][i] = sum_k Wc[k][c] x2[i][k] ----------------
__global__ __launch_bounds__(256, 2) void gemm_hc(const unsigned short* __restrict__ A,  // Wct [32][2048]
                                                  const unsigned short* __restrict__ B,  // x2 [6000][2048]
                                                  unsigned short* __restrict__ hct) {    // [32][NPAD]
    int w = threadIdx.x >> 6, l = threadIdx.x & 63;
    int lrow = l & 31, kh = l >> 5;
    int nbase = blockIdx.x * 128 + w * 32;
    int brow = nbase + lrow; if (brow > NN - 1) brow = NN - 1;
    f32x16 acc = (f32x16)0.0f;
    const short8* ap = (const short8*)(A + (size_t)lrow * FTOT + kh * 8);
    const short8* bp = (const short8*)(B + (size_t)brow * FTOT + kh * 8);
    for (int kk = 0; kk < FTOT / 16; ++kk) {
        short8 af = ap[kk * 2];
        short8 bf = bp[kk * 2];
        acc = __builtin_amdgcn_mfma_f32_32x32x16_bf16(af, bf, acc, 0, 0, 0);
    }
    int i = nbase + lrow;   // col = i
#pragma unroll
    for (int g = 0; g < 4; ++g) {
        int c0 = (g << 3) + (kh << 2);
#pragma unroll
        for (int r = 0; r < 4; ++r)
            hct[(size_t)(c0 + r) * NPAD + i] = f2bf(acc[g * 4 + r]);
    }
}

// ---------------- launcher ----------------
extern "C" void kernel_launch(void* const* d_in, const int* in_sizes, int n_in,
                              void* d_out, int out_size, void* d_ws, size_t ws_size,
                              hipStream_t stream) {
    const float* features = (const float*)d_in[0];
    const int*   adj      = (const int*)d_in[1];
    const float* W0       = (const float*)d_in[2];
    const float* a10      = (const float*)d_in[3];
    const float* a20      = (const float*)d_in[4];
    const float* Wc       = (const float*)d_in[5];
    const float* a1c      = (const float*)d_in[6];
    const float* a2c      = (const float*)d_in[7];
    float* out = (float*)d_out;

    char* p = (char*)d_ws;
    auto alloc = [&](size_t bytes) { char* r = p; p += (bytes + 255) & ~(size_t)255; return r; };
    unsigned long long* mask = (unsigned long long*)alloc((size_t)NN * MSTR * 8);
    unsigned short* Xbf = (unsigned short*)alloc((size_t)NN * DF * 2);
    unsigned short* Wt  = (unsigned short*)alloc((size_t)FTOT * DF * 2);
    unsigned short* Ht  = (unsigned short*)alloc((size_t)FTOT * NPAD * 2);
    unsigned short* x2  = (unsigned short*)alloc((size_t)NN * FTOT * 2);
    unsigned short* Wct = (unsigned short*)alloc((size_t)NC * FTOT * 2);
    unsigned short* hct = (unsigned short*)alloc((size_t)NC * NPAD * 2);
    float* f1  = (float*)alloc((size_t)NH * NPAD * 4);
    float* f2  = (float*)alloc((size_t)NH * NPAD * 4);
    float* RA  = (float*)alloc((size_t)NH * NPAD * 4);
    float* RB  = (float*)alloc((size_t)NH * NPAD * 4);
    float* F2  = (float*)alloc((size_t)NH * NPAD * 4);
    float* F2b = (float*)alloc((size_t)NH * NPAD * 4);
    float* f1c  = (float*)alloc((size_t)NPAD * 4);
    float* f2c  = (float*)alloc((size_t)NPAD * 4);
    float* RAc  = (float*)alloc((size_t)NPAD * 4);
    float* RBc  = (float*)alloc((size_t)NPAD * 4);
    float* F2c  = (float*)alloc((size_t)NPAD * 4);
    float* F2cb = (float*)alloc((size_t)NPAD * 4);

    pack_bits<<<NN, 256, 0, stream>>>(adj, mask);
    cast_x<<<(NN * DF + 255) / 256, 256, 0, stream>>>(features, Xbf, NN * DF);
    wt_pack<<<(NH * DF * HID + 255) / 256, 256, 0, stream>>>(W0, Wt);
    wct_pack<<<(FTOT * NC + 255) / 256, 256, 0, stream>>>(Wc, Wct);

    gemm_h<<<dim3(NPAD / 128, FTOT / 128), 256, 0, stream>>>(Xbf, Wt, Ht);
    f12_kern<<<dim3((NPAD + 255) / 256, NH), 256, 0, stream>>>(Ht, a10, a20, f1, f2, HID);
    prep_rows<<<(NH * NPAD) / 4, 256, 0, stream>>>(mask, f1, f2, RA, RB, NH);
    prep_f2s<<<(NH * NPAD + 255) / 256, 256, 0, stream>>>(f2, F2, F2b, NH * NPAD);

    attn_kern<HID, true><<<dim3(NPAD / 128, NH), 256, 0, stream>>>(Ht, mask, RA, RB, F2, F2b, x2, nullptr);

    gemm_hc<<<NPAD / 128, 256, 0, stream>>>(Wct, x2, hct);
    f12_kern<<<dim3((NPAD + 255) / 256, 1), 256, 0, stream>>>(hct, a1c, a2c, f1c, f2c, NC);
    prep_rows<<<NPAD / 4, 256, 0, stream>>>(mask, f1c, f2c, RAc, RBc, 1);
    prep_f2s<<<(NPAD + 255) / 256, 256, 0, stream>>>(f2c, F2c, F2cb, NPAD);

    attn_kern<NC, false><<<dim3(NPAD / 128, 1), 256, 0, stream>>>(hct, mask, RAc, RBc, F2c, F2cb, nullptr, out);
}